// Round 12
// baseline (96.636 us; speedup 1.0000x reference)
//
#include <hip/hip_runtime.h>

#define NBINS 256
#define NBUCK 4096            // 2^12 bit-space buckets (sign+exp+3 mantissa bits)
#define BSHIFT 20             // f2o(x) >> 20 -> bucket index
#define P1BLK 2048            // pass1 blocks: 8/CU (16.4 KB LDS each), 32 waves/CU
#define NCPY 2                // LDS histogram copies (selected by lane&1)
#define CSTRIDE 2049          // words; 2049 % 32 == 1 -> copies offset by one bank
#define RG 64                 // reduceA row groups (2048/64 = 32 rows each)
#define CG2 2                 // reduceA col groups

// ws layout (uint32 word offsets):
//   [0 .. 2*P1BLK)   per-block ordered min/max pairs (u[2b], u[2b+1])
//   HOFF_W           P1BLK x NBUCK partial hists, PACKED USHORT (NBUCK/2 words/row)
//   MOFF_W           RG x NBUCK reduced partials (u32)
//   FOFF_W           final NBUCK histogram (u32)
#define HOFF_W 4096u
#define MOFF_W (HOFF_W + (unsigned)P1BLK * (NBUCK / 2))   // 4,198,400
#define FOFF_W (MOFF_W + (unsigned)RG * NBUCK)            // 4,460,544

typedef float f32x4 __attribute__((ext_vector_type(4)));

__device__ __forceinline__ unsigned int f2o(float f) {
    unsigned int u = __float_as_uint(f);
    // branch-free order-preserving map: 3 VALU (ashr, or, xor)
    return u ^ ((unsigned int)(((int)u) >> 31) | 0x80000000u);
}
__device__ __forceinline__ float o2f(unsigned int u) {
    unsigned int v = (u & 0x80000000u) ? (u & 0x7fffffffu) : ~u;
    return __uint_as_float(v);
}
__device__ __forceinline__ unsigned int umn(unsigned int a, unsigned int b) { return a < b ? a : b; }
__device__ __forceinline__ unsigned int umx(unsigned int a, unsigned int b) { return a > b ? a : b; }

// n16 = n/16; each thread consumes four contiguous float4 (64 B) per iteration,
// loaded nontemporally (input is streamed exactly once - skip L2/L3 fill).
// LDS: 2 histogram copies (lane&1), u16 counters packed in u32 words
// (bucket k -> word k>>1, half k&1). Per-block per-bucket count <= n/P1BLK =
// 32768, so low-half adds never carry into the high half, and the dump-time
// packed sum of the two copies stays < 65536 per bucket.
__global__ void __launch_bounds__(256) hrt_pass1(const f32x4* __restrict__ in, int n16,
                                                 unsigned int* __restrict__ wsu) {
    __shared__ unsigned int h[NCPY * CSTRIDE];
    for (int i = threadIdx.x; i < NCPY * CSTRIDE; i += 256) h[i] = 0u;
    __syncthreads();
    unsigned int mnu = 0xFFFFFFFFu, mxu = 0u;
    unsigned int cbase = (threadIdx.x & 1u) * CSTRIDE;

#define PROC4(v) { \
    unsigned int u0 = f2o(v.x), u1 = f2o(v.y), u2 = f2o(v.z), u3 = f2o(v.w); \
    mnu = umn(mnu, umn(umn(u0, u1), umn(u2, u3))); \
    mxu = umx(mxu, umx(umx(u0, u1), umx(u2, u3))); \
    unsigned int k0 = u0 >> BSHIFT, k1 = u1 >> BSHIFT, k2 = u2 >> BSHIFT, k3 = u3 >> BSHIFT; \
    atomicAdd(&h[cbase + (k0 >> 1)], (k0 & 1u) ? 0x10000u : 1u); \
    atomicAdd(&h[cbase + (k1 >> 1)], (k1 & 1u) ? 0x10000u : 1u); \
    atomicAdd(&h[cbase + (k2 >> 1)], (k2 & 1u) ? 0x10000u : 1u); \
    atomicAdd(&h[cbase + (k3 >> 1)], (k3 & 1u) ? 0x10000u : 1u); }

    int stride = P1BLK * 256;
    for (int i = blockIdx.x * 256 + threadIdx.x; i < n16; i += stride) {
        f32x4 v0 = __builtin_nontemporal_load(&in[4 * i]);
        f32x4 v1 = __builtin_nontemporal_load(&in[4 * i + 1]);
        f32x4 v2 = __builtin_nontemporal_load(&in[4 * i + 2]);
        f32x4 v3 = __builtin_nontemporal_load(&in[4 * i + 3]);
        PROC4(v0); PROC4(v1); PROC4(v2); PROC4(v3);
    }
#undef PROC4

    #pragma unroll
    for (int off = 32; off > 0; off >>= 1) {
        mnu = umn(mnu, (unsigned int)__shfl_down((int)mnu, off));
        mxu = umx(mxu, (unsigned int)__shfl_down((int)mxu, off));
    }
    __shared__ unsigned int smn[4], smx[4];
    int lane = threadIdx.x & 63, wid = threadIdx.x >> 6;
    if (lane == 0) { smn[wid] = mnu; smx[wid] = mxu; }
    __syncthreads();
    if (threadIdx.x == 0) {
        #pragma unroll
        for (int w = 1; w < 4; ++w) { mnu = umn(mnu, smn[w]); mxu = umx(mxu, smx[w]); }
        wsu[2 * blockIdx.x]     = mnu;
        wsu[2 * blockIdx.x + 1] = mxu;
    }
    __syncthreads();
    // dump: sum the two copies; rows stay in reduceA's packed-ushort format
    unsigned int* row = wsu + HOFF_W + (unsigned)blockIdx.x * (NBUCK / 2);
    for (int k = threadIdx.x; k < NBUCK / 2; k += 256)
        row[k] = h[k] + h[CSTRIDE + k];
}

// 128 blocks: 64 row-groups (32 rows) x 2 col-groups; 1 uint4 (8 buckets)/thread
__global__ void __launch_bounds__(256) hrt_reduceA(unsigned int* __restrict__ wsu) {
    int rg = blockIdx.x >> 1, cg = blockIdx.x & 1, t = threadIdx.x;
    const uint4* src = (const uint4*)(wsu + HOFF_W);  // row = NBUCK/8 = 512 uint4
    unsigned int s[8] = {0, 0, 0, 0, 0, 0, 0, 0};
    int base = cg * 256 + t;                          // uint4 index within row
    int r0 = rg * (P1BLK / RG);
    for (int r = r0; r < r0 + P1BLK / RG; ++r) {
        uint4 v = src[r * (NBUCK / 8) + base];
        s[0] += v.x & 0xFFFFu; s[1] += v.x >> 16;
        s[2] += v.y & 0xFFFFu; s[3] += v.y >> 16;
        s[4] += v.z & 0xFFFFu; s[5] += v.z >> 16;
        s[6] += v.w & 0xFFFFu; s[7] += v.w >> 16;
    }
    uint4* dst = (uint4*)(wsu + MOFF_W);              // row = NBUCK/4 = 1024 uint4
    dst[rg * (NBUCK / 4) + base * 2]     = make_uint4(s[0], s[1], s[2], s[3]);
    dst[rg * (NBUCK / 4) + base * 2 + 1] = make_uint4(s[4], s[5], s[6], s[7]);
}

__global__ void __launch_bounds__(256) hrt_reduceB(unsigned int* __restrict__ wsu) {
    int b = blockIdx.x, t = threadIdx.x;
    const uint4* src = (const uint4*)(wsu + MOFF_W);
    uint4 s = make_uint4(0u, 0u, 0u, 0u);
    int base = b * 256 + t;
    for (int r = 0; r < RG; ++r) {
        uint4 v = src[r * (NBUCK / 4) + base];
        s.x += v.x; s.y += v.y; s.z += v.z; s.w += v.w;
    }
    ((uint4*)(wsu + FOFF_W))[base] = s;
}

__global__ void __launch_bounds__(1024) hrt_finalize(const unsigned int* __restrict__ wsu,
                                                     float* __restrict__ out) {
    __shared__ unsigned int excl[NBUCK + 1];
    __shared__ unsigned int ssum[1024];
    __shared__ unsigned int redmn[16], redmx[16];
    __shared__ float sm[2];
    int t = threadIdx.x;

    unsigned int mnu = 0xFFFFFFFFu, mxu = 0u;
    for (int i = t; i < P1BLK; i += 1024) {
        mnu = umn(mnu, wsu[2 * i]);
        mxu = umx(mxu, wsu[2 * i + 1]);
    }
    #pragma unroll
    for (int off = 32; off > 0; off >>= 1) {
        mnu = umn(mnu, (unsigned int)__shfl_down((int)mnu, off));
        mxu = umx(mxu, (unsigned int)__shfl_down((int)mxu, off));
    }
    int lane = t & 63, wid = t >> 6;
    if (lane == 0) { redmn[wid] = mnu; redmx[wid] = mxu; }

    // 4 buckets per thread
    const uint4* fh = (const uint4*)(wsu + FOFF_W);
    uint4 a = fh[t];
    unsigned int c[4] = { a.x, a.y, a.z, a.w };
    unsigned int s4 = c[0] + c[1] + c[2] + c[3];
    ssum[t] = s4;
    __syncthreads();

    for (int off = 1; off < 1024; off <<= 1) {
        unsigned int v = ssum[t];
        if (t >= off) v += ssum[t - off];
        __syncthreads();
        ssum[t] = v;
        __syncthreads();
    }
    unsigned int run = ssum[t] - s4;
    #pragma unroll
    for (int j = 0; j < 4; ++j) { excl[4 * t + j] = run; run += c[j]; }
    if (t == 1023) excl[NBUCK] = run;

    if (t == 0) {
        unsigned int m1 = 0xFFFFFFFFu, m2 = 0u;
        #pragma unroll
        for (int w = 0; w < 16; ++w) { m1 = umn(m1, redmn[w]); m2 = umx(m2, redmx[w]); }
        sm[0] = o2f(m1); sm[1] = o2f(m2);
    }
    __syncthreads();

    if (t < NBINS) {
        double mn = (double)sm[0], mx = (double)sm[1];
        unsigned int total = excl[NBUCK];
        double delta = (mx - mn) / (double)NBINS;
        double thr0 = (double)total * ((1.0 - 0.99) / 2.0);
        double thr1 = (double)total * ((1.0 + 0.99) / 2.0);

        auto estcum = [&](double e) -> double {
            unsigned int u = f2o((float)e);
            unsigned int k = u >> BSHIFT;
            unsigned int lou = k << BSHIFT;
            unsigned int hiu = (k == NBUCK - 1) ? 0xFFFFFFFFu : ((k + 1) << BSHIFT);
            double flo = (double)o2f(lou), fhi = (double)o2f(hiu);
            double fr = (e - flo) / (fhi - flo);
            fr = fr < 0.0 ? 0.0 : (fr > 1.0 ? 1.0 : fr);
            double cl = (double)excl[k], ch = (double)excl[k + 1];
            return cl + (ch - cl) * fr;
        };

        double c_hi = estcum(mn + (double)(t + 1) * delta);
        double c_lo = estcum(mn + (double)t * delta);
        if (c_hi > thr0 && !(c_lo > thr0)) out[0] = (float)(mn + (double)t * delta);
        if (c_hi > thr1 && !(c_lo > thr1)) out[1] = (float)(mn + (double)t * delta);
    }
}

extern "C" void kernel_launch(void* const* d_in, const int* in_sizes, int n_in,
                              void* d_out, int out_size, void* d_ws, size_t ws_size,
                              hipStream_t stream) {
    const f32x4* in = (const f32x4*)d_in[0];
    int n = in_sizes[0];
    int n16 = n / 16;
    unsigned int* wsu = (unsigned int*)d_ws;
    float* out = (float*)d_out;

    hrt_pass1<<<P1BLK, 256, 0, stream>>>(in, n16, wsu);
    hrt_reduceA<<<RG * CG2, 256, 0, stream>>>(wsu);
    hrt_reduceB<<<4, 256, 0, stream>>>(wsu);
    hrt_finalize<<<1, 1024, 0, stream>>>(wsu, out);
}

// Round 13
// 61.917 us; speedup vs baseline: 1.5608x; 1.5608x over previous
//
#include <hip/hip_runtime.h>

#define NBINS 256
#define NBUCK 4096            // 2^12 bit-space buckets (sign+exp+3 mantissa bits)
#define BSHIFT 20             // f2o(x) >> 20 -> bucket index
#define P1BLK 2048            // pass1 blocks: 8/CU (16.4 KB LDS each), 32 waves/CU
#define NCPY 2                // LDS histogram copies (selected by lane&1)
#define CSTRIDE 2049          // words; 2049 % 32 == 1 -> copies offset by one bank
#define RG 64                 // reduceA row groups (2048/64 = 32 rows each)
#define CG2 2                 // reduceA col groups

// ws layout (uint32 word offsets):
//   [0 .. 2*P1BLK)   per-block ordered min/max pairs (u[2b], u[2b+1])
//   HOFF_W           P1BLK x NBUCK partial hists, PACKED USHORT (NBUCK/2 words/row)
//   MOFF_W           RG x NBUCK reduced partials (u32)
//   FOFF_W           final NBUCK histogram (u32)
#define HOFF_W 4096u
#define MOFF_W (HOFF_W + (unsigned)P1BLK * (NBUCK / 2))   // 4,198,400
#define FOFF_W (MOFF_W + (unsigned)RG * NBUCK)            // 4,460,544

__device__ __forceinline__ unsigned int f2o(float f) {
    unsigned int u = __float_as_uint(f);
    return (u & 0x80000000u) ? ~u : (u | 0x80000000u);
}
__device__ __forceinline__ float o2f(unsigned int u) {
    unsigned int v = (u & 0x80000000u) ? (u & 0x7fffffffu) : ~u;
    return __uint_as_float(v);
}
__device__ __forceinline__ unsigned int umn(unsigned int a, unsigned int b) { return a < b ? a : b; }
__device__ __forceinline__ unsigned int umx(unsigned int a, unsigned int b) { return a > b ? a : b; }

// n16 = n/16; each thread consumes four contiguous float4 (64 B) per iteration.
// LDS: 2 histogram copies (lane&1), u16 counters packed in u32 words
// (bucket k -> word k>>1, half k&1). Per-block per-bucket count <= n/P1BLK =
// 32768, so low-half adds never carry into the high half, and the dump-time
// packed sum of the two copies stays < 65536 per bucket.
__global__ void __launch_bounds__(256) hrt_pass1(const float4* __restrict__ in, int n16,
                                                 unsigned int* __restrict__ wsu) {
    __shared__ unsigned int h[NCPY * CSTRIDE];
    for (int i = threadIdx.x; i < NCPY * CSTRIDE; i += 256) h[i] = 0u;
    __syncthreads();
    unsigned int mnu = 0xFFFFFFFFu, mxu = 0u;
    unsigned int cbase = (threadIdx.x & 1u) * CSTRIDE;

#define PROC4(v) { \
    unsigned int u0 = f2o(v.x), u1 = f2o(v.y), u2 = f2o(v.z), u3 = f2o(v.w); \
    mnu = umn(mnu, umn(umn(u0, u1), umn(u2, u3))); \
    mxu = umx(mxu, umx(umx(u0, u1), umx(u2, u3))); \
    unsigned int k0 = u0 >> BSHIFT, k1 = u1 >> BSHIFT, k2 = u2 >> BSHIFT, k3 = u3 >> BSHIFT; \
    atomicAdd(&h[cbase + (k0 >> 1)], (k0 & 1u) ? 0x10000u : 1u); \
    atomicAdd(&h[cbase + (k1 >> 1)], (k1 & 1u) ? 0x10000u : 1u); \
    atomicAdd(&h[cbase + (k2 >> 1)], (k2 & 1u) ? 0x10000u : 1u); \
    atomicAdd(&h[cbase + (k3 >> 1)], (k3 & 1u) ? 0x10000u : 1u); }

    int stride = P1BLK * 256;
    for (int i = blockIdx.x * 256 + threadIdx.x; i < n16; i += stride) {
        float4 v0 = in[4 * i];
        float4 v1 = in[4 * i + 1];
        float4 v2 = in[4 * i + 2];
        float4 v3 = in[4 * i + 3];
        PROC4(v0); PROC4(v1); PROC4(v2); PROC4(v3);
    }
#undef PROC4

    #pragma unroll
    for (int off = 32; off > 0; off >>= 1) {
        mnu = umn(mnu, (unsigned int)__shfl_down((int)mnu, off));
        mxu = umx(mxu, (unsigned int)__shfl_down((int)mxu, off));
    }
    __shared__ unsigned int smn[4], smx[4];
    int lane = threadIdx.x & 63, wid = threadIdx.x >> 6;
    if (lane == 0) { smn[wid] = mnu; smx[wid] = mxu; }
    __syncthreads();
    if (threadIdx.x == 0) {
        #pragma unroll
        for (int w = 1; w < 4; ++w) { mnu = umn(mnu, smn[w]); mxu = umx(mxu, smx[w]); }
        wsu[2 * blockIdx.x]     = mnu;
        wsu[2 * blockIdx.x + 1] = mxu;
    }
    __syncthreads();
    // dump: sum the two copies; rows are already in reduceA's packed format
    unsigned int* row = wsu + HOFF_W + (unsigned)blockIdx.x * (NBUCK / 2);
    for (int k = threadIdx.x; k < NBUCK / 2; k += 256)
        row[k] = h[k] + h[CSTRIDE + k];
}

// 128 blocks: 64 row-groups (32 rows) x 2 col-groups; 1 uint4 (8 buckets)/thread
__global__ void __launch_bounds__(256) hrt_reduceA(unsigned int* __restrict__ wsu) {
    int rg = blockIdx.x >> 1, cg = blockIdx.x & 1, t = threadIdx.x;
    const uint4* src = (const uint4*)(wsu + HOFF_W);  // row = NBUCK/8 = 512 uint4
    unsigned int s[8] = {0, 0, 0, 0, 0, 0, 0, 0};
    int base = cg * 256 + t;                          // uint4 index within row
    int r0 = rg * (P1BLK / RG);
    for (int r = r0; r < r0 + P1BLK / RG; ++r) {
        uint4 v = src[r * (NBUCK / 8) + base];
        s[0] += v.x & 0xFFFFu; s[1] += v.x >> 16;
        s[2] += v.y & 0xFFFFu; s[3] += v.y >> 16;
        s[4] += v.z & 0xFFFFu; s[5] += v.z >> 16;
        s[6] += v.w & 0xFFFFu; s[7] += v.w >> 16;
    }
    uint4* dst = (uint4*)(wsu + MOFF_W);              // row = NBUCK/4 = 1024 uint4
    dst[rg * (NBUCK / 4) + base * 2]     = make_uint4(s[0], s[1], s[2], s[3]);
    dst[rg * (NBUCK / 4) + base * 2 + 1] = make_uint4(s[4], s[5], s[6], s[7]);
}

__global__ void __launch_bounds__(256) hrt_reduceB(unsigned int* __restrict__ wsu) {
    int b = blockIdx.x, t = threadIdx.x;
    const uint4* src = (const uint4*)(wsu + MOFF_W);
    uint4 s = make_uint4(0u, 0u, 0u, 0u);
    int base = b * 256 + t;
    for (int r = 0; r < RG; ++r) {
        uint4 v = src[r * (NBUCK / 4) + base];
        s.x += v.x; s.y += v.y; s.z += v.z; s.w += v.w;
    }
    ((uint4*)(wsu + FOFF_W))[base] = s;
}

__global__ void __launch_bounds__(1024) hrt_finalize(const unsigned int* __restrict__ wsu,
                                                     float* __restrict__ out) {
    __shared__ unsigned int excl[NBUCK + 1];
    __shared__ unsigned int ssum[1024];
    __shared__ unsigned int redmn[16], redmx[16];
    __shared__ float sm[2];
    int t = threadIdx.x;

    unsigned int mnu = 0xFFFFFFFFu, mxu = 0u;
    for (int i = t; i < P1BLK; i += 1024) {
        mnu = umn(mnu, wsu[2 * i]);
        mxu = umx(mxu, wsu[2 * i + 1]);
    }
    #pragma unroll
    for (int off = 32; off > 0; off >>= 1) {
        mnu = umn(mnu, (unsigned int)__shfl_down((int)mnu, off));
        mxu = umx(mxu, (unsigned int)__shfl_down((int)mxu, off));
    }
    int lane = t & 63, wid = t >> 6;
    if (lane == 0) { redmn[wid] = mnu; redmx[wid] = mxu; }

    // 4 buckets per thread
    const uint4* fh = (const uint4*)(wsu + FOFF_W);
    uint4 a = fh[t];
    unsigned int c[4] = { a.x, a.y, a.z, a.w };
    unsigned int s4 = c[0] + c[1] + c[2] + c[3];
    ssum[t] = s4;
    __syncthreads();

    for (int off = 1; off < 1024; off <<= 1) {
        unsigned int v = ssum[t];
        if (t >= off) v += ssum[t - off];
        __syncthreads();
        ssum[t] = v;
        __syncthreads();
    }
    unsigned int run = ssum[t] - s4;
    #pragma unroll
    for (int j = 0; j < 4; ++j) { excl[4 * t + j] = run; run += c[j]; }
    if (t == 1023) excl[NBUCK] = run;

    if (t == 0) {
        unsigned int m1 = 0xFFFFFFFFu, m2 = 0u;
        #pragma unroll
        for (int w = 0; w < 16; ++w) { m1 = umn(m1, redmn[w]); m2 = umx(m2, redmx[w]); }
        sm[0] = o2f(m1); sm[1] = o2f(m2);
    }
    __syncthreads();

    if (t < NBINS) {
        double mn = (double)sm[0], mx = (double)sm[1];
        unsigned int total = excl[NBUCK];
        double delta = (mx - mn) / (double)NBINS;
        double thr0 = (double)total * ((1.0 - 0.99) / 2.0);
        double thr1 = (double)total * ((1.0 + 0.99) / 2.0);

        auto estcum = [&](double e) -> double {
            unsigned int u = f2o((float)e);
            unsigned int k = u >> BSHIFT;
            unsigned int lou = k << BSHIFT;
            unsigned int hiu = (k == NBUCK - 1) ? 0xFFFFFFFFu : ((k + 1) << BSHIFT);
            double flo = (double)o2f(lou), fhi = (double)o2f(hiu);
            double fr = (e - flo) / (fhi - flo);
            fr = fr < 0.0 ? 0.0 : (fr > 1.0 ? 1.0 : fr);
            double cl = (double)excl[k], ch = (double)excl[k + 1];
            return cl + (ch - cl) * fr;
        };

        double c_hi = estcum(mn + (double)(t + 1) * delta);
        double c_lo = estcum(mn + (double)t * delta);
        if (c_hi > thr0 && !(c_lo > thr0)) out[0] = (float)(mn + (double)t * delta);
        if (c_hi > thr1 && !(c_lo > thr1)) out[1] = (float)(mn + (double)t * delta);
    }
}

extern "C" void kernel_launch(void* const* d_in, const int* in_sizes, int n_in,
                              void* d_out, int out_size, void* d_ws, size_t ws_size,
                              hipStream_t stream) {
    const float4* in = (const float4*)d_in[0];
    int n = in_sizes[0];
    int n16 = n / 16;
    unsigned int* wsu = (unsigned int*)d_ws;
    float* out = (float*)d_out;

    hrt_pass1<<<P1BLK, 256, 0, stream>>>(in, n16, wsu);
    hrt_reduceA<<<RG * CG2, 256, 0, stream>>>(wsu);
    hrt_reduceB<<<4, 256, 0, stream>>>(wsu);
    hrt_finalize<<<1, 1024, 0, stream>>>(wsu, out);
}